// Round 1
// baseline (1108.759 us; speedup 1.0000x reference)
//
#include <hip/hip_runtime.h>

#define BB 8
#define LL 512
#define DD 512
#define HH 8
#define DH 64
#define BLD (BB*LL*DD)      // 2097152

typedef _Float16 f16;
typedef f16 f16x8 __attribute__((ext_vector_type(8)));
typedef float f32x4 __attribute__((ext_vector_type(4)));

// MFMA 16x16x32 f16 fragment layouts (per cdna4 docs, m89/m120-verified family):
//   A: lane holds A[m=lane&15][k=(lane>>4)*8 + j], j=0..7
//   B: lane holds B[k=(lane>>4)*8 + j][n=lane&15]
//   D: lane reg r holds D[row=(lane>>4)*4 + r][col=lane&15]

__device__ inline f16x8 ldg_cvt8(const float* __restrict__ p){
  float4 a = *(const float4*)p;
  float4 b = *(const float4*)(p+4);
  f16x8 r;
  r[0]=(f16)a.x; r[1]=(f16)a.y; r[2]=(f16)a.z; r[3]=(f16)a.w;
  r[4]=(f16)b.x; r[5]=(f16)b.y; r[6]=(f16)b.z; r[7]=(f16)b.w;
  return r;
}
__device__ inline f16x8 ldg_f16x8(const f16* __restrict__ p){ return *(const f16x8*)p; }

// ---------------- K1 / K4: Y[M,N] = X[M,K] @ W[N,K]^T + bias, f16-MFMA ----------------
// MODE 0: q proj -> scale 1/8, store f16 qh[b][h][l][e]
// MODE 1: k proj -> store f16 kh[b][h][l][e]
// MODE 2: v proj -> store f16 vth[b][h][e][l]   (transposed for ctx B-frags)
// MODE 3: out proj -> store fp32 d_out[m*512+n]
template<int MODE>
__global__ __launch_bounds__(256) void gemm_xwT(const float* __restrict__ X,
        const float* __restrict__ W, const float* __restrict__ bias,
        f16* __restrict__ oh, float* __restrict__ of)
{
  int tid = threadIdx.x;
  int w = tid >> 6, lane = tid & 63;
  int l15 = lane & 15, quad = lane >> 4;
  int m0 = blockIdx.x*64 + w*16;
  int n0 = blockIdx.y*64;
  const float* arow = X + (size_t)(m0 + l15)*DD;
  const float* brow[4];
#pragma unroll
  for(int nt=0;nt<4;nt++) brow[nt] = W + (size_t)(n0 + nt*16 + l15)*DD;
  f32x4 acc[4];
#pragma unroll
  for(int nt=0;nt<4;nt++) acc[nt] = (f32x4){0.f,0.f,0.f,0.f};
  for(int ks=0; ks<16; ks++){
    int k0 = ks*32 + quad*8;
    f16x8 a = ldg_cvt8(arow + k0);
#pragma unroll
    for(int nt=0;nt<4;nt++){
      f16x8 b = ldg_cvt8(brow[nt] + k0);
      acc[nt] = __builtin_amdgcn_mfma_f32_16x16x32_f16(a, b, acc[nt], 0,0,0);
    }
  }
#pragma unroll
  for(int nt=0;nt<4;nt++){
    int n = n0 + nt*16 + l15;     // D col = lane&15
    float bb = bias[n];
#pragma unroll
    for(int r=0;r<4;r++){
      int m = m0 + quad*4 + r;    // D row
      float v = acc[nt][r] + bb;
      if (MODE==0) v *= 0.125f;
      if (MODE==3){
        of[(size_t)m*DD + n] = v;
      } else {
        int b_ = m >> 9, l = m & 511;
        int h  = n >> 6, e = n & 63;
        size_t idx;
        if (MODE==2) idx = ((size_t)(b_*HH+h)*DH + e)*LL + l;
        else         idx = ((size_t)(b_*HH+h)*LL + l)*DH + e;
        oh[idx] = (f16)v;
      }
    }
  }
}

// ---------------- K1b: qs[b,h,l,e] = sum_d qh[b,h,l,d] * Wsk[d,e] ----------------
__global__ __launch_bounds__(256) void qs_kernel(const f16* __restrict__ qh,
        const float* __restrict__ Wsk, f16* __restrict__ qsh)
{
  int row = blockIdx.x*4 + (threadIdx.x>>6);   // (b*H+h)*L + l
  int e = threadIdx.x & 63;
  const f16* qr = qh + (size_t)row*DH;
  float acc = 0.f;
#pragma unroll 8
  for(int d=0; d<DH; d++) acc += (float)qr[d] * Wsk[d*DH + e];
  qsh[(size_t)row*DH + e] = (f16)acc;
}

// ---------------- K2a: s_struct[b,qj,h,ki] = sum_e qs[b,h,qj,e]*struct[b,qj,ki,e] ----------------
// One wave per (b,qj). M = 8 heads padded to 16.
__global__ __launch_bounds__(256) void struct_score(const f16* __restrict__ qsh,
        const float* __restrict__ st, f16* __restrict__ sst)
{
  int w = threadIdx.x >> 6, lane = threadIdx.x & 63;
  int l15 = lane & 15, quad = lane >> 4;
  int qj = blockIdx.x*4 + w;
  int b = blockIdx.y;
  f16x8 aF[2];
#pragma unroll
  for(int ks=0;ks<2;ks++)
    aF[ks] = ldg_f16x8(qsh + ((size_t)(b*HH + (l15&7))*LL + qj)*DH + ks*32 + quad*8);
  const float* sbase = st + ((size_t)b*LL + qj)*LL*DH;
  for(int nt=0; nt<32; nt++){
    int ki0 = nt*16;
    f32x4 acc = (f32x4){0.f,0.f,0.f,0.f};
#pragma unroll
    for(int ks=0;ks<2;ks++){
      f16x8 bF = ldg_cvt8(sbase + (size_t)(ki0 + l15)*DH + ks*32 + quad*8);
      acc = __builtin_amdgcn_mfma_f32_16x16x32_f16(aF[ks], bF, acc, 0,0,0);
    }
    if (quad < 2){
#pragma unroll
      for(int r=0;r<4;r++){
        int h = quad*4 + r;
        sst[((size_t)(b*LL + qj)*HH + h)*LL + ki0 + l15] = (f16)acc[r];
      }
    }
  }
}

// ---------------- K2b: scores = qk + s_struct; softmax; attn out; ctx1 = attn@v ----------------
// Block (256) per (b, h, 16-row q-tile). Wave w owns ki in [w*128, w*128+128).
__global__ __launch_bounds__(256) void attn_kernel(const f16* __restrict__ qh,
        const f16* __restrict__ kh, const f16* __restrict__ sst, const f16* __restrict__ vth,
        f16* __restrict__ attn, float* __restrict__ ctx, float* __restrict__ out_attn0)
{
  __shared__ f16  plds[4*16*136];      // per-wave [16 qj][128+pad ki] normalized probs
  __shared__ float ldsm[16][4];
  __shared__ float ldsl[16][4];
  __shared__ float clds[4][16][64];
  int w = threadIdx.x>>6, lane = threadIdx.x&63;
  int l15 = lane&15, quad = lane>>4;
  int q0 = blockIdx.x*16, h = blockIdx.y, b = blockIdx.z;

  f16x8 aQ[2];
#pragma unroll
  for(int ks=0;ks<2;ks++)
    aQ[ks] = ldg_f16x8(qh + ((size_t)(b*HH+h)*LL + q0 + l15)*DH + ks*32 + quad*8);

  f32x4 sc[8];
#pragma unroll
  for(int nt=0;nt<8;nt++) sc[nt] = (f32x4){0.f,0.f,0.f,0.f};
  for(int nt=0; nt<8; nt++){
    int ki0 = w*128 + nt*16;
#pragma unroll
    for(int ks=0;ks<2;ks++){
      f16x8 bF = ldg_f16x8(kh + ((size_t)(b*HH+h)*LL + ki0 + l15)*DH + ks*32 + quad*8);
      sc[nt] = __builtin_amdgcn_mfma_f32_16x16x32_f16(aQ[ks], bF, sc[nt], 0,0,0);
    }
  }
  // add structural bias (ALPHA=1)
#pragma unroll
  for(int nt=0;nt<8;nt++){
#pragma unroll
    for(int r=0;r<4;r++){
      sc[nt][r] += (float)sst[((size_t)(b*LL + q0+quad*4+r)*HH + h)*LL + w*128 + nt*16 + l15];
    }
  }
  // row max over this wave's 128 ki
  float mp[4];
#pragma unroll
  for(int r=0;r<4;r++){
    float m = sc[0][r];
#pragma unroll
    for(int nt=1;nt<8;nt++) m = fmaxf(m, sc[nt][r]);
#pragma unroll
    for(int msk=1;msk<16;msk<<=1) m = fmaxf(m, __shfl_xor(m, msk));
    mp[r] = m;
  }
  if (l15==0){
#pragma unroll
    for(int r=0;r<4;r++) ldsm[quad*4+r][w] = mp[r];
  }
  __syncthreads();
  float mg[4];
#pragma unroll
  for(int r=0;r<4;r++){
    float4 mv = *(const float4*)&ldsm[quad*4+r][0];
    mg[r] = fmaxf(fmaxf(mv.x,mv.y),fmaxf(mv.z,mv.w));
  }
  float lp[4] = {0.f,0.f,0.f,0.f};
#pragma unroll
  for(int nt=0;nt<8;nt++){
#pragma unroll
    for(int r=0;r<4;r++){
      float p = __expf(sc[nt][r]-mg[r]);
      sc[nt][r] = p; lp[r] += p;
    }
  }
#pragma unroll
  for(int r=0;r<4;r++){
#pragma unroll
    for(int msk=1;msk<16;msk<<=1) lp[r] += __shfl_xor(lp[r], msk);
  }
  if (l15==0){
#pragma unroll
    for(int r=0;r<4;r++) ldsl[quad*4+r][w] = lp[r];
  }
  __syncthreads();
  float inv[4];
#pragma unroll
  for(int r=0;r<4;r++){
    float4 lv = *(const float4*)&ldsl[quad*4+r][0];
    inv[r] = 1.f/(lv.x+lv.y+lv.z+lv.w);
  }
  // write normalized attn (global f16 + own-wave LDS) and head-0 fp32 output
  f16* pw = plds + w*2176;
#pragma unroll
  for(int nt=0;nt<8;nt++){
#pragma unroll
    for(int r=0;r<4;r++){
      float a = sc[nt][r]*inv[r];
      int row = quad*4 + r;
      int ki = w*128 + nt*16 + l15;
      attn[((size_t)(b*HH+h)*LL + q0+row)*LL + ki] = (f16)a;
      pw[row*136 + nt*16 + l15] = (f16)a;
      if (h==0) out_attn0[(size_t)(b*LL + q0+row)*LL + ki] = a;
    }
  }
  // ctx partial: attn(16 x 128) @ v(128 x 64); wave-private LDS, in-order DS pipe
  f32x4 c4[4];
#pragma unroll
  for(int nt=0;nt<4;nt++) c4[nt] = (f32x4){0.f,0.f,0.f,0.f};
#pragma unroll
  for(int ks=0;ks<4;ks++){
    f16x8 aP = *(const f16x8*)&pw[l15*136 + ks*32 + quad*8];
#pragma unroll
    for(int nt=0;nt<4;nt++){
      f16x8 bV = ldg_f16x8(vth + ((size_t)(b*HH+h)*DH + nt*16 + l15)*LL + w*128 + ks*32 + quad*8);
      c4[nt] = __builtin_amdgcn_mfma_f32_16x16x32_f16(aP, bV, c4[nt], 0,0,0);
    }
  }
#pragma unroll
  for(int nt=0;nt<4;nt++){
#pragma unroll
    for(int r=0;r<4;r++) clds[w][quad*4+r][nt*16+l15] = c4[nt][r];
  }
  __syncthreads();
  int t = threadIdx.x;
#pragma unroll
  for(int i=0;i<4;i++){
    int idx = t + i*256;
    int qj = idx>>6, e = idx&63;
    float s = clds[0][qj][e]+clds[1][qj][e]+clds[2][qj][e]+clds[3][qj][e];
    ctx[((size_t)(b*LL + q0+qj))*DD + h*DH + e] = s;
  }
}

// ---------------- K3: t = attn @ struct (per b,qj); ctx += t@Wsv^T + bsv ----------------
// One wave per (b,qj). Structure tile transposed into LDS for B-frags.
__global__ __launch_bounds__(256) void t_ctx_kernel(const f16* __restrict__ attn,
        const float* __restrict__ st, const float* __restrict__ Wsv,
        const float* __restrict__ bsv, float* __restrict__ ctx)
{
  __shared__ f16  stT[4][64*136];   // per wave: [e][128+pad ki]
  __shared__ float tl[4][8*64];     // per wave: t[h][e]
  int w = threadIdx.x>>6, lane = threadIdx.x&63;
  int l15 = lane&15, quad = lane>>4;
  int qj = blockIdx.x*4 + w;
  int b = blockIdx.y;
  const float* sbase = st + ((size_t)b*LL + qj)*LL*DH;
  const f16* abase = attn + ((size_t)(b*HH + (l15&7))*LL + qj)*LL;  // A row m = head
  f16* myT = stT[w];
  f32x4 tacc[4];
#pragma unroll
  for(int nt=0;nt<4;nt++) tacc[nt] = (f32x4){0.f,0.f,0.f,0.f};

  for(int kt=0; kt<4; kt++){
    int kb = kt*128;
    __syncthreads();
    // cooperative (wave-local) load + transpose: 128 ki x 64 e
    int e4 = l15*4;
#pragma unroll 4
    for(int i=0;i<32;i++){
      int ki = i*4 + quad;
      float4 v = *(const float4*)(sbase + (size_t)(kb + ki)*DH + e4);
      myT[(e4+0)*136 + ki] = (f16)v.x;
      myT[(e4+1)*136 + ki] = (f16)v.y;
      myT[(e4+2)*136 + ki] = (f16)v.z;
      myT[(e4+3)*136 + ki] = (f16)v.w;
    }
    __syncthreads();
#pragma unroll
    for(int ks=0; ks<4; ks++){
      f16x8 aA = ldg_f16x8(abase + kb + ks*32 + quad*8);
#pragma unroll
      for(int nt=0;nt<4;nt++){
        f16x8 bS = *(const f16x8*)&myT[(nt*16+l15)*136 + ks*32 + quad*8];
        tacc[nt] = __builtin_amdgcn_mfma_f32_16x16x32_f16(aA, bS, tacc[nt], 0,0,0);
      }
    }
  }
  if (quad < 2){
#pragma unroll
    for(int nt=0;nt<4;nt++){
#pragma unroll
      for(int r=0;r<4;r++) tl[w][(quad*4+r)*64 + nt*16 + l15] = tacc[nt][r];
    }
  }
  __syncthreads();
  // ctx2[h][d] = sum_e t[h][e]*Wsv[d][e]; ctx += ctx2 + bsv[d]
  int d = lane;
  const float4* Wsv4 = (const float4*)Wsv;
  float* base = ctx + ((size_t)(b*LL + qj))*DD;
  float bv = bsv[d];
  for(int h=0; h<8; h++){
    float s2 = 0.f;
#pragma unroll
    for(int q4=0; q4<16; q4++){
      float4 wv = Wsv4[d*16 + q4];
      float4 tt = *(const float4*)&tl[w][h*64 + q4*4];
      s2 += wv.x*tt.x + wv.y*tt.y + wv.z*tt.z + wv.w*tt.w;
    }
    base[h*64 + d] += s2 + bv;
  }
}

// ---------------- launch ----------------
extern "C" void kernel_launch(void* const* d_in, const int* in_sizes, int n_in,
                              void* d_out, int out_size, void* d_ws, size_t ws_size,
                              hipStream_t stream)
{
  const float* query = (const float*)d_in[0];
  const float* key   = (const float*)d_in[1];
  const float* value = (const float*)d_in[2];
  const float* st    = (const float*)d_in[3];
  const float* Wq = (const float*)d_in[4];  const float* bq = (const float*)d_in[5];
  const float* Wk = (const float*)d_in[6];  const float* bk = (const float*)d_in[7];
  const float* Wv = (const float*)d_in[8];  const float* bv = (const float*)d_in[9];
  const float* Wsk= (const float*)d_in[10];
  const float* Wsv= (const float*)d_in[12]; const float* bsv= (const float*)d_in[13];
  const float* Wo = (const float*)d_in[14]; const float* bo = (const float*)d_in[15];

  char* ws = (char*)d_ws;
  f16* qh   = (f16*)(ws);                  //  4 MB  q/8, [b][h][l][e]
  f16* qsh  = (f16*)(ws + 4194304);        //  4 MB  q@Wsk
  f16* kh   = (f16*)(ws + 8388608);        //  4 MB
  f16* vth  = (f16*)(ws + 12582912);       //  4 MB  [b][h][e][l]
  f16* sst  = (f16*)(ws + 16777216);       // 32 MB  [b][qj][h][ki]
  f16* attn = (f16*)(ws + 50331648);       // 32 MB  [b][h][qj][ki]
  float* ctx = (float*)(ws + 83886080);    //  8 MB  [b][l][h*64+e]
  float* outp  = (float*)d_out;
  float* attn0 = outp + BLD;

  dim3 blk(256);
  gemm_xwT<0><<<dim3(64,8),blk,0,stream>>>(query, Wq, bq, qh, nullptr);
  gemm_xwT<1><<<dim3(64,8),blk,0,stream>>>(key,   Wk, bk, kh, nullptr);
  gemm_xwT<2><<<dim3(64,8),blk,0,stream>>>(value, Wv, bv, vth, nullptr);
  qs_kernel<<<dim3(8192),blk,0,stream>>>(qh, Wsk, qsh);
  struct_score<<<dim3(128,8),blk,0,stream>>>(qsh, st, sst);
  attn_kernel<<<dim3(32,8,8),blk,0,stream>>>(qh, kh, sst, vth, attn, ctx, attn0);
  t_ctx_kernel<<<dim3(128,8),blk,0,stream>>>(attn, st, Wsv, bsv, ctx);
  gemm_xwT<3><<<dim3(64,8),blk,0,stream>>>(ctx, Wo, bo, nullptr, outp);
}